// Round 1
// baseline (487.509 us; speedup 1.0000x reference)
//
#include <hip/hip_runtime.h>
#include <math.h>

#define BB 512
#define DD 16
#define NN 64
#define MM 32
#define RR 32
#define CC 10
#define BBLK 16   // b's per workgroup in chain_kernel

// ---------------------------------------------------------------------------
// Kernel 1: feat[b,d,m] = sum_n tensor[b,d,n] * W[n,m] + bias[m]
// one thread per (b,d,m) output element
// ---------------------------------------------------------------------------
__global__ void feat_kernel(const float* __restrict__ tensor,
                            const float* __restrict__ W,
                            const float* __restrict__ bias,
                            float* __restrict__ feat) {
    int t  = blockIdx.x * blockDim.x + threadIdx.x;   // 0 .. B*D*M-1
    int m  = t & (MM - 1);
    int bd = t >> 5;
    const float* tp = tensor + bd * NN;
    float acc = bias[m];
#pragma unroll
    for (int n = 0; n < NN; ++n) acc += tp[n] * W[n * MM + m];
    feat[t] = acc;
}

// ---------------------------------------------------------------------------
// Kernel 2: per (c, b-block of 16): build cores on the fly and chain-multiply.
//   core[c,d,b][i][j] = sum_m feat[b,d,m] * G[c,d,i,m,j]
//   prod_b = core(d=0) @ core(d=1) @ ... @ core(d=15);  logits[b,c] = trace
// Phase-1 layout: thread (j = t&31, ig = t>>5) computes core rows
//                 i = h*16 + ig*2 + {0,1} for all 16 b, half-chunk h in {0,1}.
// Phase-2 layout: thread (b2 = t>>4, rp = t&15) owns prod rows 2rp, 2rp+1 of b2.
// core half-chunk lives in LDS (padded +4 floats per b to avoid 4-way bank
// conflicts on the b2-strided broadcast reads).
// ---------------------------------------------------------------------------
__global__ __launch_bounds__(256) void chain_kernel(
    const float* __restrict__ feat,   // [B][D][M]
    const float* __restrict__ G,      // [C][D][R][M][R]
    float* __restrict__ logits)       // [B][C]
{
    __shared__ __align__(16) float feat_sT[MM][BBLK];        // [m][b], 2 KB
    __shared__ __align__(16) float core_s[BBLK][16 * RR + 4]; // half-chunk, 33 KB

    const int bid = blockIdx.x;         // 0..319
    const int c   = bid % CC;
    const int b0  = (bid / CC) * BBLK;
    const int t   = threadIdx.x;

    // phase-1 indices
    const int j  = t & 31;
    const int ig = t >> 5;              // 0..7
    // phase-2 indices
    const int b2 = t >> 4;              // 0..15
    const int rp = t & 15;
    const int i0 = rp * 2, i1 = rp * 2 + 1;

    float p0[RR], p1[RR], q0[RR], q1[RR];

    for (int d = 0; d < DD; ++d) {
        __syncthreads();   // prev-iter P1 feat reads done; safe to restage
        {   // stage feat_sT[m][b] for this d (512 elements, 2 per thread)
            int e0 = t, e1 = t + 256;
            feat_sT[e0 >> 4][e0 & 15] =
                feat[(b0 + (e0 & 15)) * (DD * MM) + d * MM + (e0 >> 4)];
            feat_sT[e1 >> 4][e1 & 15] =
                feat[(b0 + (e1 & 15)) * (DD * MM) + d * MM + (e1 >> 4)];
        }
        if (d > 0) {
#pragma unroll
            for (int x = 0; x < RR; ++x) { q0[x] = 0.f; q1[x] = 0.f; }
        }
        const float* Gd = G + (size_t)(c * DD + d) * (RR * MM * RR);

#pragma unroll
        for (int h = 0; h < 2; ++h) {
            __syncthreads();  // feat staged / prev half's P2 reads of core_s done
            // ---- Phase 1: core rows i = h*16 + ig*2 + {0,1}, all 16 b ----
            {
                float a0[BBLK], a1[BBLK];
#pragma unroll
                for (int b = 0; b < BBLK; ++b) { a0[b] = 0.f; a1[b] = 0.f; }
                const int irow = h * 16 + ig * 2;
                const float* Gp0 = Gd + irow * (MM * RR) + j;
                const float* Gp1 = Gp0 + MM * RR;
#pragma unroll 4
                for (int m = 0; m < MM; ++m) {
                    float g0 = Gp0[m * RR];
                    float g1 = Gp1[m * RR];
                    const float4* fv =
                        reinterpret_cast<const float4*>(&feat_sT[m][0]);
#pragma unroll
                    for (int v = 0; v < 4; ++v) {
                        float4 f = fv[v];
                        a0[v*4+0] += g0 * f.x; a0[v*4+1] += g0 * f.y;
                        a0[v*4+2] += g0 * f.z; a0[v*4+3] += g0 * f.w;
                        a1[v*4+0] += g1 * f.x; a1[v*4+1] += g1 * f.y;
                        a1[v*4+2] += g1 * f.z; a1[v*4+3] += g1 * f.w;
                    }
                }
                const int kk0 = ig * 2;
#pragma unroll
                for (int b = 0; b < BBLK; ++b) {
                    core_s[b][kk0 * RR + j]       = a0[b];
                    core_s[b][(kk0 + 1) * RR + j] = a1[b];
                }
            }
            __syncthreads();
            // ---- Phase 2 ----
            if (d == 0) {
                // prod = core(d=0): load this thread's two rows (if in half h)
                if ((i0 >> 4) == h) {
                    const float4* r0 = reinterpret_cast<const float4*>(
                        &core_s[b2][(i0 & 15) * RR]);
                    const float4* r1 = reinterpret_cast<const float4*>(
                        &core_s[b2][(i1 & 15) * RR]);
#pragma unroll
                    for (int v = 0; v < 8; ++v) {
                        float4 x0 = r0[v], x1 = r1[v];
                        p0[v*4+0] = x0.x; p0[v*4+1] = x0.y;
                        p0[v*4+2] = x0.z; p0[v*4+3] = x0.w;
                        p1[v*4+0] = x1.x; p1[v*4+1] = x1.y;
                        p1[v*4+2] = x1.z; p1[v*4+3] = x1.w;
                    }
                }
            } else {
                // q += p[:, h*16:h*16+16] @ core_half
#pragma unroll
                for (int kk = 0; kk < 16; ++kk) {
                    const float a0 = p0[h * 16 + kk];
                    const float a1 = p1[h * 16 + kk];
                    const float4* cv =
                        reinterpret_cast<const float4*>(&core_s[b2][kk * RR]);
#pragma unroll
                    for (int v = 0; v < 8; ++v) {
                        float4 cc = cv[v];
                        q0[v*4+0] += a0 * cc.x; q0[v*4+1] += a0 * cc.y;
                        q0[v*4+2] += a0 * cc.z; q0[v*4+3] += a0 * cc.w;
                        q1[v*4+0] += a1 * cc.x; q1[v*4+1] += a1 * cc.y;
                        q1[v*4+2] += a1 * cc.z; q1[v*4+3] += a1 * cc.w;
                    }
                }
            }
        }
        if (d > 0) {
#pragma unroll
            for (int x = 0; x < RR; ++x) { p0[x] = q0[x]; p1[x] = q1[x]; }
        }
    }

    // trace: this thread holds rows i0, i1 of prod → diag elems p0[i0], p1[i1]
    float tr = 0.f;
#pragma unroll
    for (int x = 0; x < RR; ++x) {
        if (x == i0) tr += p0[x];
        if (x == i1) tr += p1[x];
    }
#pragma unroll
    for (int off = 8; off > 0; off >>= 1)
        tr += __shfl_down(tr, off, 16);
    if (rp == 0) logits[(b0 + b2) * CC + c] = tr;
}

// ---------------------------------------------------------------------------
// Kernel 3: log_softmax over c (one thread per b)
// ---------------------------------------------------------------------------
__global__ void lsm_kernel(const float* __restrict__ logits,
                           float* __restrict__ out) {
    int b = blockIdx.x * blockDim.x + threadIdx.x;
    if (b >= BB) return;
    float x[CC];
    float mx = -1e30f;
#pragma unroll
    for (int c = 0; c < CC; ++c) { x[c] = logits[b * CC + c]; mx = fmaxf(mx, x[c]); }
    float s = 0.f;
#pragma unroll
    for (int c = 0; c < CC; ++c) s += expf(x[c] - mx);
    float ls = logf(s);
#pragma unroll
    for (int c = 0; c < CC; ++c) out[b * CC + c] = x[c] - mx - ls;
}

// ---------------------------------------------------------------------------
extern "C" void kernel_launch(void* const* d_in, const int* in_sizes, int n_in,
                              void* d_out, int out_size, void* d_ws, size_t ws_size,
                              hipStream_t stream) {
    const float* tensor = (const float*)d_in[0];
    const float* W      = (const float*)d_in[1];
    const float* bias   = (const float*)d_in[2];
    const float* G      = (const float*)d_in[3];
    float* out    = (float*)d_out;
    float* feat   = (float*)d_ws;                 // B*D*M = 262144 floats (1 MB)
    float* logits = feat + BB * DD * MM;          // B*C = 5120 floats

    feat_kernel<<<(BB * DD * MM) / 256, 256, 0, stream>>>(tensor, W, bias, feat);
    chain_kernel<<<CC * (BB / BBLK), 256, 0, stream>>>(feat, G, logits);
    lsm_kernel<<<(BB + 255) / 256, 256, 0, stream>>>(logits, out);
}